// Round 12
// baseline (774.331 us; speedup 1.0000x reference)
//
#include <hip/hip_runtime.h>
#include <hip/hip_bf16.h>

#define LN_EPS 1e-5f
#define AVG_K 151
#define AVG_HALF 75

typedef __attribute__((ext_vector_type(8))) short short8v;
typedef __attribute__((ext_vector_type(4))) float float4v;

static __device__ inline unsigned short f2bf(float f) {
  union { __hip_bfloat16 h; unsigned short u; } cv;
  cv.h = __float2bfloat16(f);
  return cv.u;
}

// ---------------- block reduce ----------------
__device__ inline float blockReduceSum(float val, float* tmp) {
  #pragma unroll
  for (int off = 32; off > 0; off >>= 1) val += __shfl_down(val, off, 64);
  int lane = threadIdx.x & 63;
  int wid  = threadIdx.x >> 6;
  __syncthreads();
  if (lane == 0) tmp[wid] = val;
  __syncthreads();
  int nw = blockDim.x >> 6;
  val = (threadIdx.x < nw) ? tmp[threadIdx.x] : 0.f;
  if (wid == 0) {
    #pragma unroll
    for (int off = 32; off > 0; off >>= 1) val += __shfl_down(val, off, 64);
  }
  return val;  // valid on thread 0
}

// ---------------- 1: fused reduce_x + weight prep ----------------
__global__ void k_pre(const float* __restrict__ x, int L,
                      const float* __restrict__ W1a, const float* __restrict__ b1a,
                      const float* __restrict__ W1b, const float* __restrict__ b1b,
                      const float* __restrict__ W2a, const float* __restrict__ b2a,
                      const float* __restrict__ W2b, const float* __restrict__ b2b,
                      float* __restrict__ eps1, float* __restrict__ eps2,
                      unsigned short* __restrict__ Wb1, unsigned short* __restrict__ Wb2,
                      float* __restrict__ sums) {
  __shared__ float tmp[16];
  const int b = blockIdx.x;
  if (b < 1024) {
    float s = 0.f, ss = 0.f;
    for (int j = b * blockDim.x + threadIdx.x; j < L; j += 1024 * blockDim.x) {
      float val = x[j];
      s += val; ss += val * val;
    }
    float bs  = blockReduceSum(s, tmp);
    float bss = blockReduceSum(ss, tmp);
    if (threadIdx.x == 0) { atomicAdd(&sums[0], bs); atomicAdd(&sums[1], bss); }
    return;
  }
  const int tid0 = (b - 1024) * blockDim.x + threadIdx.x;
  const int nth  = 64 * 256;
  for (int n = tid0; n < 272; n += nth) {
    float ba = 0.f, waD = 0.f, wbe = 0.f;
    if (n < 260) {
      ba = b1a[n];
      waD = W1a[n * 65 + 64];
      float s = 0.f;
      #pragma unroll
      for (int p = 0; p < 3; ++p) s += W1b[p * 260 + n];
      wbe = s * (1.f / 3.f);
    }
    eps1[4 * n + 0] = ba; eps1[4 * n + 1] = waD; eps1[4 * n + 2] = wbe; eps1[4 * n + 3] = 0.f;
  }
  for (int n = tid0; n < 528; n += nth) {
    float ba = 0.f, waD = 0.f, wbe = 0.f;
    if (n < 516) {
      ba = b2a[n];
      waD = W2a[n * 129 + 128];
      float s = 0.f;
      for (int p = 0; p < 21; ++p) s += W2b[p * 516 + n];
      wbe = s * (1.f / 21.f);
    }
    eps2[4 * n + 0] = ba; eps2[4 * n + 1] = waD; eps2[4 * n + 2] = wbe; eps2[4 * n + 3] = 0.f;
  }
  for (int idx = tid0; idx < 272 * 64; idx += nth) {
    int n = idx >> 6, k = idx & 63;
    Wb1[idx] = (n < 260) ? f2bf(W1a[n * 65 + k]) : (unsigned short)0;
  }
  for (int idx = tid0; idx < 528 * 128; idx += nth) {
    int n = idx >> 7, k = idx & 127;
    Wb2[idx] = (n < 516) ? f2bf(W2a[n * 129 + k]) : (unsigned short)0;
  }
  if (tid0 == 0) {
    float s = 0.f;
    #pragma unroll
    for (int p = 0; p < 3; ++p) s += b1b[p];
    sums[6] = s * (1.f / 3.f);
    s = 0.f;
    for (int p = 0; p < 21; ++p) s += b2b[p];
    sums[7] = s * (1.f / 21.f);
  }
}

// ---------------- 2: fused normalize + avgpool (LDS halo) ----------------
__global__ __launch_bounds__(256) void k_norm_pool(
    const float* __restrict__ x, const float* __restrict__ sums,
    unsigned short* __restrict__ vb, float* __restrict__ avg,
    float* __restrict__ energy, int L) {
  __shared__ float sv[256 + 2 * AVG_HALF];
  const int tid = threadIdx.x;
  const int j0 = blockIdx.x * 256;
  const float mean = sums[0] / (float)L;
  const float var  = sums[1] / (float)L - mean * mean;
  const float rstd = rsqrtf(var + LN_EPS);
  for (int m = tid; m < 256 + 2 * AVG_HALF; m += 256) {
    int idx = j0 - AVG_HALF + m;
    sv[m] = (idx >= 0 && idx < L) ? (x[idx] - mean) * rstd : 0.f;
  }
  __syncthreads();
  vb[j0 + tid] = f2bf(sv[AVG_HALF + tid]);
  float s = 0.f, e = 0.f;
  #pragma unroll 1
  for (int t = 0; t < AVG_K; ++t) {
    float val = sv[tid + t];
    s += val;
    e += val * val;
  }
  avg[j0 + tid]    = s * (1.f / AVG_K);
  energy[j0 + tid] = e * (1.f / AVG_K);
}

// ---------------- 3/4: MFMA band-GEMM branch, LDS-staged B, 2-phase dbuf ----------------
template <int K, int NT, bool DIVE>
__device__ __forceinline__ void branch_body(
    const unsigned short* __restrict__ vb, const float* __restrict__ avg,
    const float* __restrict__ energy,
    const unsigned short* __restrict__ Wb, const float* __restrict__ eps,
    float* __restrict__ sums, int bb_slot, int sum_slot,
    float* __restrict__ t, int L) {
  constexpr int MR  = 4;
  constexpr int BM  = 256;
  constexpr int KB  = K / 32;
  constexpr int RC  = BM + K;
  constexpr int RCP = RC + 8;
  constexpr int ROWB16 = K / 8;
  constexpr int STH = 16 * ROWB16;
  constexpr int NEPS = NT * 16;

  __shared__ unsigned short rc[8 * RCP];
  __shared__ float4 epsl[NEPS];
  __shared__ unsigned short btile[2][16 * K];

  const int tid  = threadIdx.x;
  const int lane = tid & 63;
  const int w    = tid >> 6;
  const int j0   = blockIdx.x * BM;
  const int mask = L - 1;
  const int jtop = j0 + BM - 1;

  for (int idx = tid; idx < 8 * RC; idx += 256) {
    int c = idx / RC;
    int m = idx - c * RC;
    rc[c * RCP + m] = vb[(jtop - m - c + L) & mask];
  }
  const float4* eps4 = (const float4*)eps;
  for (int i = tid; i < NEPS; i += 256) epsl[i] = eps4[i];

  const bool sact = tid < STH;
  int dst_blk = 0;
  short8v breg;
  if (sact) {
    dst_blk = tid ^ ((tid / ROWB16) & 7);
    breg = *(const short8v*)&Wb[tid * 8];
    *(short8v*)&btile[0][dst_blk * 8] = breg;
    if (NT > 1) breg = *(const short8v*)&Wb[16 * K + tid * 8];
  }
  __syncthreads();

  const int ll = lane & 15;
  const int h  = lane >> 4;
  const int s  = (15 - ll) + 8 * h;
  const int cidx  = s & 7;
  const int sbase = s & ~7;

  short8v afrag[MR][KB];
  #pragma unroll
  for (int mr = 0; mr < MR; ++mr) {
    #pragma unroll
    for (int kb = 0; kb < KB; ++kb) {
      const int B0 = BM - 16 - 64 * w - 16 * mr + 32 * kb;
      afrag[mr][kb] = *(const short8v*)&rc[cidx * RCP + B0 + sbase];
    }
  }

  float avgreg[MR][4];
  #pragma unroll
  for (int mr = 0; mr < MR; ++mr)
    #pragma unroll
    for (int r = 0; r < 4; ++r)
      avgreg[mr][r] = avg[j0 + 64 * w + 16 * mr + 4 * h + r];

  float rowacc[MR][4];
  #pragma unroll
  for (int mr = 0; mr < MR; ++mr)
    #pragma unroll
    for (int r = 0; r < 4; ++r) rowacc[mr][r] = 0.f;

  for (int nt = 0; nt < NT; ++nt) {
    const int cur = nt & 1;
    short8v bfrag[KB];
    #pragma unroll
    for (int kb = 0; kb < KB; ++kb) {
      const int ba = (ll * (2 * K) + kb * 64 + h * 16) ^ ((ll & 7) << 4);
      bfrag[kb] = *(const short8v*)((const char*)&btile[cur][0] + ba);
    }
    const float4 ep = epsl[nt * 16 + ll];

    #pragma unroll
    for (int mr = 0; mr < MR; ++mr) {
      float4v acc;
      #pragma unroll
      for (int r = 0; r < 4; ++r) acc[r] = fmaf(avgreg[mr][r], ep.y, ep.x);
      #pragma unroll
      for (int kb = 0; kb < KB; ++kb)
        acc = __builtin_amdgcn_mfma_f32_16x16x32_bf16(afrag[mr][kb], bfrag[kb], acc, 0, 0, 0);
      #pragma unroll
      for (int r = 0; r < 4; ++r) rowacc[mr][r] += fmaxf(acc[r], 0.f) * ep.z;
    }

    if (nt + 1 < NT) {
      if (sact) {
        *(short8v*)&btile[cur ^ 1][dst_blk * 8] = breg;
        if (nt + 2 < NT) breg = *(const short8v*)&Wb[(nt + 2) * 16 * K + tid * 8];
      }
    }
    __syncthreads();
  }

  #pragma unroll
  for (int mr = 0; mr < MR; ++mr)
    #pragma unroll
    for (int r = 0; r < 4; ++r) {
      float vsum = rowacc[mr][r];
      vsum += __shfl_xor(vsum, 1);
      vsum += __shfl_xor(vsum, 2);
      vsum += __shfl_xor(vsum, 4);
      vsum += __shfl_xor(vsum, 8);
      rowacc[mr][r] = vsum;
    }

  const float bb = sums[bb_slot];
  float su = 0.f, suu = 0.f;
  #pragma unroll
  for (int mr = 0; mr < MR; ++mr)
    #pragma unroll
    for (int r = 0; r < 4; ++r) {
      const int row = j0 + 64 * w + 16 * mr + 4 * h + r;
      float val = rowacc[mr][r] + bb;
      if (DIVE) val /= energy[row];
      su += val; suu += val * val;
      if (ll == 0) t[row] = val;
    }

  #pragma unroll
  for (int off = 1; off <= 32; off <<= 1) {
    su  += __shfl_xor(su, off);
    suu += __shfl_xor(suu, off);
  }
  if (lane == 0) {
    atomicAdd(&sums[sum_slot],     su  * (1.f / 16.f));
    atomicAdd(&sums[sum_slot + 1], suu * (1.f / 16.f));
  }
}

__global__ __launch_bounds__(256) void k_branch1(
    const unsigned short* __restrict__ vb, const float* __restrict__ avg,
    const float* __restrict__ energy,
    const unsigned short* __restrict__ Wb, const float* __restrict__ eps,
    float* __restrict__ sums, float* __restrict__ t, int L) {
  branch_body<64, 17, true>(vb, avg, energy, Wb, eps, sums, 6, 2, t, L);
}

__global__ __launch_bounds__(256) void k_branch2(
    const unsigned short* __restrict__ vb, const float* __restrict__ avg,
    const float* __restrict__ energy,
    const unsigned short* __restrict__ Wb, const float* __restrict__ eps,
    float* __restrict__ sums, float* __restrict__ t, int L) {
  branch_body<128, 33, false>(vb, avg, energy, Wb, eps, sums, 7, 4, t, L);
}

// ---------------- diagnostic ablation variants (branch1 geometry, scratch outputs) ----
// VAR 0: full copy. VAR 1: no atomics. VAR 2: no MFMA loop (prologue+epilogue).
// VAR 3: prologue only. Keepalive via opaque runtime guard (sums[0] > 1e30 is false).
template <int VAR>
__device__ __forceinline__ void abl_body(
    const unsigned short* __restrict__ vb, const float* __restrict__ avg,
    const float* __restrict__ energy,
    const unsigned short* __restrict__ Wb, const float* __restrict__ eps,
    const float* __restrict__ sums, float* __restrict__ tscr,
    float* __restrict__ sscr, int L) {
  constexpr int K = 64, NT = 17, MR = 4, BM = 256;
  constexpr int KB = K / 32, RC = BM + K, RCP = RC + 8;
  constexpr int ROWB16 = K / 8, STH = 16 * ROWB16, NEPS = NT * 16;

  __shared__ unsigned short rc[8 * RCP];
  __shared__ float4 epsl[NEPS];
  __shared__ unsigned short btile[2][16 * K];

  const int tid = threadIdx.x, lane = tid & 63, w = tid >> 6;
  const int j0 = blockIdx.x * BM, mask = L - 1, jtop = j0 + BM - 1;
  const bool guard = sums[0] > 1e30f;   // runtime-false, opaque to compiler

  for (int idx = tid; idx < 8 * RC; idx += 256) {
    int c = idx / RC, m = idx - c * RC;
    rc[c * RCP + m] = vb[(jtop - m - c + L) & mask];
  }
  const float4* eps4 = (const float4*)eps;
  for (int i = tid; i < NEPS; i += 256) epsl[i] = eps4[i];

  const bool sact = tid < STH;
  int dst_blk = 0;
  short8v breg;
  if (sact) {
    dst_blk = tid ^ ((tid / ROWB16) & 7);
    breg = *(const short8v*)&Wb[tid * 8];
    *(short8v*)&btile[0][dst_blk * 8] = breg;
    breg = *(const short8v*)&Wb[16 * K + tid * 8];
  }
  __syncthreads();

  const int ll = lane & 15, h = lane >> 4;
  const int s = (15 - ll) + 8 * h, cidx = s & 7, sbase = s & ~7;

  short8v afrag[MR][KB];
  #pragma unroll
  for (int mr = 0; mr < MR; ++mr)
    #pragma unroll
    for (int kb = 0; kb < KB; ++kb) {
      const int B0 = BM - 16 - 64 * w - 16 * mr + 32 * kb;
      afrag[mr][kb] = *(const short8v*)&rc[cidx * RCP + B0 + sbase];
    }

  float avgreg[MR][4];
  #pragma unroll
  for (int mr = 0; mr < MR; ++mr)
    #pragma unroll
    for (int r = 0; r < 4; ++r)
      avgreg[mr][r] = avg[j0 + 64 * w + 16 * mr + 4 * h + r];

  float rowacc[MR][4];
  #pragma unroll
  for (int mr = 0; mr < MR; ++mr)
    #pragma unroll
    for (int r = 0; r < 4; ++r) rowacc[mr][r] = 0.f;

  float keep = 0.f;

  if (VAR <= 1) {
    for (int nt = 0; nt < NT; ++nt) {
      const int cur = nt & 1;
      short8v bfrag[KB];
      #pragma unroll
      for (int kb = 0; kb < KB; ++kb) {
        const int ba = (ll * (2 * K) + kb * 64 + h * 16) ^ ((ll & 7) << 4);
        bfrag[kb] = *(const short8v*)((const char*)&btile[cur][0] + ba);
      }
      const float4 ep = epsl[nt * 16 + ll];
      #pragma unroll
      for (int mr = 0; mr < MR; ++mr) {
        float4v acc;
        #pragma unroll
        for (int r = 0; r < 4; ++r) acc[r] = fmaf(avgreg[mr][r], ep.y, ep.x);
        #pragma unroll
        for (int kb = 0; kb < KB; ++kb)
          acc = __builtin_amdgcn_mfma_f32_16x16x32_bf16(afrag[mr][kb], bfrag[kb], acc, 0, 0, 0);
        #pragma unroll
        for (int r = 0; r < 4; ++r) rowacc[mr][r] += fmaxf(acc[r], 0.f) * ep.z;
      }
      if (nt + 1 < NT) {
        if (sact) {
          *(short8v*)&btile[cur ^ 1][dst_blk * 8] = breg;
          if (nt + 2 < NT) breg = *(const short8v*)&Wb[(nt + 2) * 16 * K + tid * 8];
        }
      }
      __syncthreads();
    }
  } else {
    // keepalive: all prologue results feed a guarded store
    int ka = 0;
    #pragma unroll
    for (int mr = 0; mr < MR; ++mr)
      #pragma unroll
      for (int kb = 0; kb < KB; ++kb) {
        const int4 p = *(const int4*)&afrag[mr][kb];
        ka += p.x + p.y + p.z + p.w;
      }
    if (sact) { const int4 pb = *(const int4*)&breg; ka += pb.x + pb.y + pb.z + pb.w; }
    volatile unsigned short* vt = &btile[0][0];
    ka += vt[tid & 1023];
    keep = (float)ka + epsl[tid & 255].x;
  }

  if (VAR == 3) {
    float kf = 0.f;
    #pragma unroll
    for (int mr = 0; mr < MR; ++mr)
      #pragma unroll
      for (int r = 0; r < 4; ++r) kf += avgreg[mr][r];
    if (guard) tscr[j0 + tid] = keep + kf;
    return;
  }

  #pragma unroll
  for (int mr = 0; mr < MR; ++mr)
    #pragma unroll
    for (int r = 0; r < 4; ++r) {
      float vsum = rowacc[mr][r];
      vsum += __shfl_xor(vsum, 1);
      vsum += __shfl_xor(vsum, 2);
      vsum += __shfl_xor(vsum, 4);
      vsum += __shfl_xor(vsum, 8);
      rowacc[mr][r] = vsum;
    }

  const float bb = sums[6];
  float su = 0.f, suu = 0.f;
  #pragma unroll
  for (int mr = 0; mr < MR; ++mr)
    #pragma unroll
    for (int r = 0; r < 4; ++r) {
      const int row = j0 + 64 * w + 16 * mr + 4 * h + r;
      float val = rowacc[mr][r] + bb;
      val /= energy[row];
      su += val; suu += val * val;
      if (ll == 0) tscr[row] = val;
    }
  #pragma unroll
  for (int off = 1; off <= 32; off <<= 1) {
    su  += __shfl_xor(su, off);
    suu += __shfl_xor(suu, off);
  }
  if (VAR == 1) {
    if (guard && lane == 0) sscr[6] = su + suu + keep;
  } else {
    if (lane == 0) {
      atomicAdd(&sscr[2], su * (1.f / 16.f));
      atomicAdd(&sscr[3], suu * (1.f / 16.f));
    }
    if (guard) tscr[j0 + tid] = keep;
  }
}

__global__ __launch_bounds__(256) void k_ablA(
    const unsigned short* vb, const float* avg, const float* energy,
    const unsigned short* Wb, const float* eps, const float* sums,
    float* tscr, float* sscr, int L) {
  abl_body<0>(vb, avg, energy, Wb, eps, sums, tscr, sscr, L);
}
__global__ __launch_bounds__(256) void k_ablB(
    const unsigned short* vb, const float* avg, const float* energy,
    const unsigned short* Wb, const float* eps, const float* sums,
    float* tscr, float* sscr, int L) {
  abl_body<1>(vb, avg, energy, Wb, eps, sums, tscr, sscr, L);
}
__global__ __launch_bounds__(256) void k_ablC(
    const unsigned short* vb, const float* avg, const float* energy,
    const unsigned short* Wb, const float* eps, const float* sums,
    float* tscr, float* sscr, int L) {
  abl_body<2>(vb, avg, energy, Wb, eps, sums, tscr, sscr, L);
}
__global__ __launch_bounds__(256) void k_ablD(
    const unsigned short* vb, const float* avg, const float* energy,
    const unsigned short* Wb, const float* eps, const float* sums,
    float* tscr, float* sscr, int L) {
  abl_body<3>(vb, avg, energy, Wb, eps, sums, tscr, sscr, L);
}

// VAR 4: entire Wb1 pre-staged in LDS, ONE barrier, no in-loop barriers.
__global__ __launch_bounds__(256) void k_abl4(
    const unsigned short* __restrict__ vb, const float* __restrict__ avg,
    const float* __restrict__ energy,
    const unsigned short* __restrict__ Wb, const float* __restrict__ eps,
    const float* __restrict__ sums, float* __restrict__ tscr,
    float* __restrict__ sscr, int L) {
  constexpr int K = 64, NT = 17, MR = 4, BM = 256;
  constexpr int KB = K / 32, RC = BM + K, RCP = RC + 8, NEPS = NT * 16;

  __shared__ unsigned short rc[8 * RCP];
  __shared__ float4 epsl[NEPS];
  __shared__ unsigned short ball[NT * 16 * K];  // 34816 B

  const int tid = threadIdx.x, lane = tid & 63, w = tid >> 6;
  const int j0 = blockIdx.x * BM, mask = L - 1, jtop = j0 + BM - 1;

  for (int idx = tid; idx < 8 * RC; idx += 256) {
    int c = idx / RC, m = idx - c * RC;
    rc[c * RCP + m] = vb[(jtop - m - c + L) & mask];
  }
  const float4* eps4 = (const float4*)eps;
  for (int i = tid; i < NEPS; i += 256) epsl[i] = eps4[i];
  for (int u = tid; u < NT * 128; u += 256) {
    int nt = u >> 7, c = u & 127;
    int dst = c ^ ((c >> 3) & 7);
    *(short8v*)&ball[nt * 1024 + dst * 8] = *(const short8v*)&Wb[u * 8];
  }
  __syncthreads();   // the ONLY barrier

  const int ll = lane & 15, h = lane >> 4;
  const int s = (15 - ll) + 8 * h, cidx = s & 7, sbase = s & ~7;

  short8v afrag[MR][KB];
  #pragma unroll
  for (int mr = 0; mr < MR; ++mr)
    #pragma unroll
    for (int kb = 0; kb < KB; ++kb) {
      const int B0 = BM - 16 - 64 * w - 16 * mr + 32 * kb;
      afrag[mr][kb] = *(const short8v*)&rc[cidx * RCP + B0 + sbase];
    }

  float avgreg[MR][4];
  #pragma unroll
  for (int mr = 0; mr < MR; ++mr)
    #pragma unroll
    for (int r = 0; r < 4; ++r)
      avgreg[mr][r] = avg[j0 + 64 * w + 16 * mr + 4 * h + r];

  float rowacc[MR][4];
  #pragma unroll
  for (int mr = 0; mr < MR; ++mr)
    #pragma unroll
    for (int r = 0; r < 4; ++r) rowacc[mr][r] = 0.f;

  #pragma unroll 1
  for (int nt = 0; nt < NT; ++nt) {
    short8v bfrag[KB];
    #pragma unroll
    for (int kb = 0; kb < KB; ++kb) {
      const int ba = nt * 2048 + ((ll * 128 + kb * 64 + h * 16) ^ ((ll & 7) << 4));
      bfrag[kb] = *(const short8v*)((const char*)&ball[0] + ba);
    }
    const float4 ep = epsl[nt * 16 + ll];
    #pragma unroll
    for (int mr = 0; mr < MR; ++mr) {
      float4v acc;
      #pragma unroll
      for (int r = 0; r < 4; ++r) acc[r] = fmaf(avgreg[mr][r], ep.y, ep.x);
      #pragma unroll
      for (int kb = 0; kb < KB; ++kb)
        acc = __builtin_amdgcn_mfma_f32_16x16x32_bf16(afrag[mr][kb], bfrag[kb], acc, 0, 0, 0);
      #pragma unroll
      for (int r = 0; r < 4; ++r) rowacc[mr][r] += fmaxf(acc[r], 0.f) * ep.z;
    }
  }

  #pragma unroll
  for (int mr = 0; mr < MR; ++mr)
    #pragma unroll
    for (int r = 0; r < 4; ++r) {
      float vsum = rowacc[mr][r];
      vsum += __shfl_xor(vsum, 1);
      vsum += __shfl_xor(vsum, 2);
      vsum += __shfl_xor(vsum, 4);
      vsum += __shfl_xor(vsum, 8);
      rowacc[mr][r] = vsum;
    }

  const float bb = sums[6];
  float su = 0.f, suu = 0.f;
  #pragma unroll
  for (int mr = 0; mr < MR; ++mr)
    #pragma unroll
    for (int r = 0; r < 4; ++r) {
      const int row = j0 + 64 * w + 16 * mr + 4 * h + r;
      float val = rowacc[mr][r] + bb;
      val /= energy[row];
      su += val; suu += val * val;
      if (ll == 0) tscr[row] = val;
    }
  #pragma unroll
  for (int off = 1; off <= 32; off <<= 1) {
    su  += __shfl_xor(su, off);
    suu += __shfl_xor(suu, off);
  }
  if (lane == 0) {
    atomicAdd(&sscr[2], su * (1.f / 16.f));
    atomicAdd(&sscr[3], suu * (1.f / 16.f));
  }
}

// ---------------- 5: final layernorms ----------------
__global__ void k_final(const float* __restrict__ t1, const float* __restrict__ t2,
                        const float* __restrict__ sums, float* __restrict__ out, int L) {
  float m1 = sums[2] / (float)L;
  float v1 = sums[3] / (float)L - m1 * m1;
  float r1 = rsqrtf(v1 + LN_EPS);
  float m2 = sums[4] / (float)L;
  float v2 = sums[5] / (float)L - m2 * m2;
  float r2 = rsqrtf(v2 + LN_EPS);
  for (int j = blockIdx.x * blockDim.x + threadIdx.x; j < L; j += gridDim.x * blockDim.x) {
    out[j]     = (t1[j] - m1) * r1;
    out[L + j] = (t2[j] - m2) * r2;
  }
}

extern "C" void kernel_launch(void* const* d_in, const int* in_sizes, int n_in,
                              void* d_out, int out_size, void* d_ws, size_t ws_size,
                              hipStream_t stream) {
  const float* x   = (const float*)d_in[0];
  const float* W1a = (const float*)d_in[1];
  const float* b1a = (const float*)d_in[2];
  const float* W1b = (const float*)d_in[3];
  const float* b1b = (const float*)d_in[4];
  const float* W2a = (const float*)d_in[5];
  const float* b2a = (const float*)d_in[6];
  const float* W2b = (const float*)d_in[7];
  const float* b2b = (const float*)d_in[8];
  float* out = (float*)d_out;

  const int L = in_sizes[0];  // 262144

  char* base = (char*)d_ws;
  float* t1     = (float*)base;                      // L
  float* t2     = t1 + L;                            // L
  float* avg    = t2 + L;                            // L
  float* energy = avg + L;                           // L
  float* sums   = energy + L;                        // 8
  float* eps1   = sums + 8;                          // 272*4
  float* eps2   = eps1 + 272 * 4;                    // 528*4
  unsigned short* vb  = (unsigned short*)(eps2 + 528 * 4);  // L
  unsigned short* Wb1 = vb + L;                      // 272*64
  unsigned short* Wb2 = Wb1 + 272 * 64;              // 528*128

  // scratch for ablation variants: avg/energy are dead after the real branches
  float* tscr = avg;
  float* sscr = energy;

  hipMemsetAsync(sums, 0, 8 * sizeof(float), stream);

  k_pre<<<1088, 256, 0, stream>>>(x, L, W1a, b1a, W1b, b1b, W2a, b2a, W2b, b2b,
                                  eps1, eps2, Wb1, Wb2, sums);
  k_norm_pool<<<L / 256, 256, 0, stream>>>(x, sums, vb, avg, energy, L);

  k_branch1<<<L / 256, 256, 0, stream>>>(vb, avg, energy, Wb1, eps1, sums, t1, L);
  k_branch2<<<L / 256, 256, 0, stream>>>(vb, avg, energy, Wb2, eps2, sums, t2, L);

  // diagnostics (timing-only; outputs go to dead scratch)
  k_ablA<<<L / 256, 256, 0, stream>>>(vb, avg, energy, Wb1, eps1, sums, tscr, sscr, L);
  k_ablB<<<L / 256, 256, 0, stream>>>(vb, avg, energy, Wb1, eps1, sums, tscr, sscr, L);
  k_ablC<<<L / 256, 256, 0, stream>>>(vb, avg, energy, Wb1, eps1, sums, tscr, sscr, L);
  k_ablD<<<L / 256, 256, 0, stream>>>(vb, avg, energy, Wb1, eps1, sums, tscr, sscr, L);
  k_abl4<<<L / 256, 256, 0, stream>>>(vb, avg, energy, Wb1, eps1, sums, tscr, sscr, L);

  k_final<<<1024, 256, 0, stream>>>(t1, t2, sums, out, L);
}

// Round 15
// 184.659 us; speedup vs baseline: 4.1933x; 4.1933x over previous
//
#include <hip/hip_runtime.h>
#include <hip/hip_bf16.h>

#define LN_EPS 1e-5f
#define AVG_K 151
#define AVG_HALF 75

typedef __attribute__((ext_vector_type(8))) short short8v;
typedef __attribute__((ext_vector_type(4))) float float4v;

static __device__ inline unsigned short f2bf(float f) {
  union { __hip_bfloat16 h; unsigned short u; } cv;
  cv.h = __float2bfloat16(f);
  return cv.u;
}

// ---------------- block reduce ----------------
__device__ inline float blockReduceSum(float val, float* tmp) {
  #pragma unroll
  for (int off = 32; off > 0; off >>= 1) val += __shfl_down(val, off, 64);
  int lane = threadIdx.x & 63;
  int wid  = threadIdx.x >> 6;
  __syncthreads();
  if (lane == 0) tmp[wid] = val;
  __syncthreads();
  int nw = blockDim.x >> 6;
  val = (threadIdx.x < nw) ? tmp[threadIdx.x] : 0.f;
  if (wid == 0) {
    #pragma unroll
    for (int off = 32; off > 0; off >>= 1) val += __shfl_down(val, off, 64);
  }
  return val;  // valid on thread 0
}

// ---------------- 1: fused reduce_x + weight prep ----------------
__global__ void k_pre(const float* __restrict__ x, int L,
                      const float* __restrict__ W1a, const float* __restrict__ b1a,
                      const float* __restrict__ W1b, const float* __restrict__ b1b,
                      const float* __restrict__ W2a, const float* __restrict__ b2a,
                      const float* __restrict__ W2b, const float* __restrict__ b2b,
                      float* __restrict__ eps1, float* __restrict__ eps2,
                      unsigned short* __restrict__ Wb1, unsigned short* __restrict__ Wb2,
                      float* __restrict__ sums) {
  __shared__ float tmp[16];
  const int b = blockIdx.x;
  if (b < 1024) {
    float s = 0.f, ss = 0.f;
    for (int j = b * blockDim.x + threadIdx.x; j < L; j += 1024 * blockDim.x) {
      float val = x[j];
      s += val; ss += val * val;
    }
    float bs  = blockReduceSum(s, tmp);
    float bss = blockReduceSum(ss, tmp);
    if (threadIdx.x == 0) { atomicAdd(&sums[0], bs); atomicAdd(&sums[1], bss); }
    return;
  }
  const int tid0 = (b - 1024) * blockDim.x + threadIdx.x;
  const int nth  = 64 * 256;
  for (int n = tid0; n < 272; n += nth) {
    float ba = 0.f, waD = 0.f, wbe = 0.f;
    if (n < 260) {
      ba = b1a[n];
      waD = W1a[n * 65 + 64];
      float s = 0.f;
      #pragma unroll
      for (int p = 0; p < 3; ++p) s += W1b[p * 260 + n];
      wbe = s * (1.f / 3.f);
    }
    eps1[4 * n + 0] = ba; eps1[4 * n + 1] = waD; eps1[4 * n + 2] = wbe; eps1[4 * n + 3] = 0.f;
  }
  for (int n = tid0; n < 528; n += nth) {
    float ba = 0.f, waD = 0.f, wbe = 0.f;
    if (n < 516) {
      ba = b2a[n];
      waD = W2a[n * 129 + 128];
      float s = 0.f;
      for (int p = 0; p < 21; ++p) s += W2b[p * 516 + n];
      wbe = s * (1.f / 21.f);
    }
    eps2[4 * n + 0] = ba; eps2[4 * n + 1] = waD; eps2[4 * n + 2] = wbe; eps2[4 * n + 3] = 0.f;
  }
  for (int idx = tid0; idx < 272 * 64; idx += nth) {
    int n = idx >> 6, k = idx & 63;
    Wb1[idx] = (n < 260) ? f2bf(W1a[n * 65 + k]) : (unsigned short)0;
  }
  for (int idx = tid0; idx < 528 * 128; idx += nth) {
    int n = idx >> 7, k = idx & 127;
    Wb2[idx] = (n < 516) ? f2bf(W2a[n * 129 + k]) : (unsigned short)0;
  }
  if (tid0 == 0) {
    float s = 0.f;
    #pragma unroll
    for (int p = 0; p < 3; ++p) s += b1b[p];
    sums[6] = s * (1.f / 3.f);
    s = 0.f;
    for (int p = 0; p < 21; ++p) s += b2b[p];
    sums[7] = s * (1.f / 21.f);
  }
}

// ---------------- 2: fused normalize + avgpool (LDS halo) ----------------
__global__ __launch_bounds__(256) void k_norm_pool(
    const float* __restrict__ x, const float* __restrict__ sums,
    unsigned short* __restrict__ vb, float* __restrict__ avg,
    float* __restrict__ energy, int L) {
  __shared__ float sv[256 + 2 * AVG_HALF];
  const int tid = threadIdx.x;
  const int j0 = blockIdx.x * 256;
  const float mean = sums[0] / (float)L;
  const float var  = sums[1] / (float)L - mean * mean;
  const float rstd = rsqrtf(var + LN_EPS);
  for (int m = tid; m < 256 + 2 * AVG_HALF; m += 256) {
    int idx = j0 - AVG_HALF + m;
    sv[m] = (idx >= 0 && idx < L) ? (x[idx] - mean) * rstd : 0.f;
  }
  __syncthreads();
  vb[j0 + tid] = f2bf(sv[AVG_HALF + tid]);
  float s = 0.f, e = 0.f;
  #pragma unroll 1
  for (int t = 0; t < AVG_K; ++t) {
    float val = sv[tid + t];
    s += val;
    e += val * val;
  }
  avg[j0 + tid]    = s * (1.f / AVG_K);
  energy[j0 + tid] = e * (1.f / AVG_K);
}

// ---------------- 3: branch1 — all-B-in-LDS, single barrier, no atomics ----------------
__global__ __launch_bounds__(256) void k_b1v4(
    const unsigned short* __restrict__ vb, const float* __restrict__ avg,
    const float* __restrict__ energy,
    const unsigned short* __restrict__ Wb, const float* __restrict__ eps,
    const float* __restrict__ sums, float* __restrict__ t,
    float* __restrict__ psumS, float* __restrict__ psumSS, int L) {
  constexpr int K = 64, NT = 17, MR = 4, BM = 256;
  constexpr int KB = K / 32, RC = BM + K, RCP = RC + 8, NEPS = NT * 16;

  __shared__ unsigned short rc[8 * RCP];
  __shared__ float4 epsl[NEPS];
  __shared__ unsigned short ball[NT * 16 * K];  // 34816 B
  __shared__ float ps[8];

  const int tid = threadIdx.x, lane = tid & 63, w = tid >> 6;
  const int j0 = blockIdx.x * BM, mask = L - 1, jtop = j0 + BM - 1;

  for (int idx = tid; idx < 8 * RC; idx += 256) {
    int c = idx / RC, m = idx - c * RC;
    rc[c * RCP + m] = vb[(jtop - m - c + L) & mask];
  }
  const float4* eps4 = (const float4*)eps;
  for (int i = tid; i < NEPS; i += 256) epsl[i] = eps4[i];
  for (int u = tid; u < NT * 128; u += 256) {
    int nt = u >> 7, c = u & 127;
    int dst = c ^ ((c >> 3) & 7);
    *(short8v*)&ball[nt * 1024 + dst * 8] = *(const short8v*)&Wb[u * 8];
  }
  __syncthreads();   // single barrier before the loop

  const int ll = lane & 15, h = lane >> 4;
  const int s = (15 - ll) + 8 * h, cidx = s & 7, sbase = s & ~7;

  short8v afrag[MR][KB];
  #pragma unroll
  for (int mr = 0; mr < MR; ++mr)
    #pragma unroll
    for (int kb = 0; kb < KB; ++kb) {
      const int B0 = BM - 16 - 64 * w - 16 * mr + 32 * kb;
      afrag[mr][kb] = *(const short8v*)&rc[cidx * RCP + B0 + sbase];
    }

  float avgreg[MR][4];
  #pragma unroll
  for (int mr = 0; mr < MR; ++mr)
    #pragma unroll
    for (int r = 0; r < 4; ++r)
      avgreg[mr][r] = avg[j0 + 64 * w + 16 * mr + 4 * h + r];

  float rowacc[MR][4];
  #pragma unroll
  for (int mr = 0; mr < MR; ++mr)
    #pragma unroll
    for (int r = 0; r < 4; ++r) rowacc[mr][r] = 0.f;

  #pragma unroll 1
  for (int nt = 0; nt < NT; ++nt) {
    short8v bfrag[KB];
    #pragma unroll
    for (int kb = 0; kb < KB; ++kb) {
      const int ba = nt * 2048 + ((ll * 128 + kb * 64 + h * 16) ^ ((ll & 7) << 4));
      bfrag[kb] = *(const short8v*)((const char*)&ball[0] + ba);
    }
    const float4 ep = epsl[nt * 16 + ll];
    #pragma unroll
    for (int mr = 0; mr < MR; ++mr) {
      float4v acc;
      #pragma unroll
      for (int r = 0; r < 4; ++r) acc[r] = fmaf(avgreg[mr][r], ep.y, ep.x);
      #pragma unroll
      for (int kb = 0; kb < KB; ++kb)
        acc = __builtin_amdgcn_mfma_f32_16x16x32_bf16(afrag[mr][kb], bfrag[kb], acc, 0, 0, 0);
      #pragma unroll
      for (int r = 0; r < 4; ++r) rowacc[mr][r] += fmaxf(acc[r], 0.f) * ep.z;
    }
  }

  #pragma unroll
  for (int mr = 0; mr < MR; ++mr)
    #pragma unroll
    for (int r = 0; r < 4; ++r) {
      float vsum = rowacc[mr][r];
      vsum += __shfl_xor(vsum, 1);
      vsum += __shfl_xor(vsum, 2);
      vsum += __shfl_xor(vsum, 4);
      vsum += __shfl_xor(vsum, 8);
      rowacc[mr][r] = vsum;
    }

  const float bb = sums[6];
  float su = 0.f, suu = 0.f;
  #pragma unroll
  for (int mr = 0; mr < MR; ++mr)
    #pragma unroll
    for (int r = 0; r < 4; ++r) {
      const int row = j0 + 64 * w + 16 * mr + 4 * h + r;
      float val = rowacc[mr][r] + bb;
      val /= energy[row];
      su += val; suu += val * val;
      if (ll == 0) t[row] = val;
    }
  #pragma unroll
  for (int off = 1; off <= 32; off <<= 1) {
    su  += __shfl_xor(su, off);
    suu += __shfl_xor(suu, off);
  }
  if (lane == 0) { ps[w] = su; ps[4 + w] = suu; }
  __syncthreads();
  if (tid == 0) {
    psumS[blockIdx.x]  = (ps[0] + ps[1] + ps[2] + ps[3]) * (1.f / 16.f);
    psumSS[blockIdx.x] = (ps[4] + ps[5] + ps[6] + ps[7]) * (1.f / 16.f);
  }
}

// ---------------- 4: branch2 — dbuf LDS staging (R10 structure), no atomics ----------
__global__ __launch_bounds__(256) void k_b2nda(
    const unsigned short* __restrict__ vb, const float* __restrict__ avg,
    const unsigned short* __restrict__ Wb, const float* __restrict__ eps,
    const float* __restrict__ sums, float* __restrict__ t,
    float* __restrict__ psumS, float* __restrict__ psumSS, int L) {
  constexpr int K = 128, NT = 33, MR = 4, BM = 256;
  constexpr int KB = K / 32, RC = BM + K, RCP = RC + 8;
  constexpr int ROWB16 = K / 8, STH = 16 * ROWB16, NEPS = NT * 16;

  __shared__ unsigned short rc[8 * RCP];
  __shared__ float4 epsl[NEPS];
  __shared__ unsigned short btile[2][16 * K];
  __shared__ float ps[8];

  const int tid = threadIdx.x, lane = tid & 63, w = tid >> 6;
  const int j0 = blockIdx.x * BM, mask = L - 1, jtop = j0 + BM - 1;

  for (int idx = tid; idx < 8 * RC; idx += 256) {
    int c = idx / RC, m = idx - c * RC;
    rc[c * RCP + m] = vb[(jtop - m - c + L) & mask];
  }
  const float4* eps4 = (const float4*)eps;
  for (int i = tid; i < NEPS; i += 256) epsl[i] = eps4[i];

  const bool sact = tid < STH;
  int dst_blk = 0;
  short8v breg;
  if (sact) {
    dst_blk = tid ^ ((tid / ROWB16) & 7);
    breg = *(const short8v*)&Wb[tid * 8];
    *(short8v*)&btile[0][dst_blk * 8] = breg;
    breg = *(const short8v*)&Wb[16 * K + tid * 8];
  }
  __syncthreads();

  const int ll = lane & 15, h = lane >> 4;
  const int s = (15 - ll) + 8 * h, cidx = s & 7, sbase = s & ~7;

  short8v afrag[MR][KB];
  #pragma unroll
  for (int mr = 0; mr < MR; ++mr)
    #pragma unroll
    for (int kb = 0; kb < KB; ++kb) {
      const int B0 = BM - 16 - 64 * w - 16 * mr + 32 * kb;
      afrag[mr][kb] = *(const short8v*)&rc[cidx * RCP + B0 + sbase];
    }

  float avgreg[MR][4];
  #pragma unroll
  for (int mr = 0; mr < MR; ++mr)
    #pragma unroll
    for (int r = 0; r < 4; ++r)
      avgreg[mr][r] = avg[j0 + 64 * w + 16 * mr + 4 * h + r];

  float rowacc[MR][4];
  #pragma unroll
  for (int mr = 0; mr < MR; ++mr)
    #pragma unroll
    for (int r = 0; r < 4; ++r) rowacc[mr][r] = 0.f;

  #pragma unroll 1
  for (int nt = 0; nt < NT; ++nt) {
    const int cur = nt & 1;
    short8v bfrag[KB];
    #pragma unroll
    for (int kb = 0; kb < KB; ++kb) {
      const int ba = (ll * (2 * K) + kb * 64 + h * 16) ^ ((ll & 7) << 4);
      bfrag[kb] = *(const short8v*)((const char*)&btile[cur][0] + ba);
    }
    const float4 ep = epsl[nt * 16 + ll];

    #pragma unroll
    for (int mr = 0; mr < MR; ++mr) {
      float4v acc;
      #pragma unroll
      for (int r = 0; r < 4; ++r) acc[r] = fmaf(avgreg[mr][r], ep.y, ep.x);
      #pragma unroll
      for (int kb = 0; kb < KB; ++kb)
        acc = __builtin_amdgcn_mfma_f32_16x16x32_bf16(afrag[mr][kb], bfrag[kb], acc, 0, 0, 0);
      #pragma unroll
      for (int r = 0; r < 4; ++r) rowacc[mr][r] += fmaxf(acc[r], 0.f) * ep.z;
    }

    if (nt + 1 < NT) {
      if (sact) {
        *(short8v*)&btile[cur ^ 1][dst_blk * 8] = breg;
        if (nt + 2 < NT) breg = *(const short8v*)&Wb[(nt + 2) * 16 * K + tid * 8];
      }
    }
    __syncthreads();
  }

  #pragma unroll
  for (int mr = 0; mr < MR; ++mr)
    #pragma unroll
    for (int r = 0; r < 4; ++r) {
      float vsum = rowacc[mr][r];
      vsum += __shfl_xor(vsum, 1);
      vsum += __shfl_xor(vsum, 2);
      vsum += __shfl_xor(vsum, 4);
      vsum += __shfl_xor(vsum, 8);
      rowacc[mr][r] = vsum;
    }

  const float bb = sums[7];
  float su = 0.f, suu = 0.f;
  #pragma unroll
  for (int mr = 0; mr < MR; ++mr)
    #pragma unroll
    for (int r = 0; r < 4; ++r) {
      const int row = j0 + 64 * w + 16 * mr + 4 * h + r;
      float val = rowacc[mr][r] + bb;
      su += val; suu += val * val;
      if (ll == 0) t[row] = val;
    }
  #pragma unroll
  for (int off = 1; off <= 32; off <<= 1) {
    su  += __shfl_xor(su, off);
    suu += __shfl_xor(suu, off);
  }
  if (lane == 0) { ps[w] = su; ps[4 + w] = suu; }
  __syncthreads();
  if (tid == 0) {
    psumS[blockIdx.x]  = (ps[0] + ps[1] + ps[2] + ps[3]) * (1.f / 16.f);
    psumSS[blockIdx.x] = (ps[4] + ps[5] + ps[6] + ps[7]) * (1.f / 16.f);
  }
}

// ---------------- 5: reduce per-block partials -> sums[2..5] ----------------
__global__ void k_psum(const float* __restrict__ psum, float* __restrict__ sums) {
  __shared__ float tmp[16];
  float v = psum[blockIdx.x * 1024 + threadIdx.x];
  float r = blockReduceSum(v, tmp);
  if (threadIdx.x == 0) sums[2 + blockIdx.x] = r;
}

// ---------------- 6: final layernorms ----------------
__global__ void k_final(const float* __restrict__ t1, const float* __restrict__ t2,
                        const float* __restrict__ sums, float* __restrict__ out, int L) {
  float m1 = sums[2] / (float)L;
  float v1 = sums[3] / (float)L - m1 * m1;
  float r1 = rsqrtf(v1 + LN_EPS);
  float m2 = sums[4] / (float)L;
  float v2 = sums[5] / (float)L - m2 * m2;
  float r2 = rsqrtf(v2 + LN_EPS);
  for (int j = blockIdx.x * blockDim.x + threadIdx.x; j < L; j += gridDim.x * blockDim.x) {
    out[j]     = (t1[j] - m1) * r1;
    out[L + j] = (t2[j] - m2) * r2;
  }
}

extern "C" void kernel_launch(void* const* d_in, const int* in_sizes, int n_in,
                              void* d_out, int out_size, void* d_ws, size_t ws_size,
                              hipStream_t stream) {
  const float* x   = (const float*)d_in[0];
  const float* W1a = (const float*)d_in[1];
  const float* b1a = (const float*)d_in[2];
  const float* W1b = (const float*)d_in[3];
  const float* b1b = (const float*)d_in[4];
  const float* W2a = (const float*)d_in[5];
  const float* b2a = (const float*)d_in[6];
  const float* W2b = (const float*)d_in[7];
  const float* b2b = (const float*)d_in[8];
  float* out = (float*)d_out;

  const int L = in_sizes[0];  // 262144

  char* base = (char*)d_ws;
  float* t1     = (float*)base;                      // L
  float* t2     = t1 + L;                            // L
  float* avg    = t2 + L;                            // L
  float* energy = avg + L;                           // L
  float* sums   = energy + L;                        // 8
  float* eps1   = sums + 8;                          // 272*4
  float* eps2   = eps1 + 272 * 4;                    // 528*4
  float* psum   = eps2 + 528 * 4;                    // 4*1024 (b1 s, b1 ss, b2 s, b2 ss)
  unsigned short* vb  = (unsigned short*)(psum + 4 * 1024);  // L
  unsigned short* Wb1 = vb + L;                      // 272*64
  unsigned short* Wb2 = Wb1 + 272 * 64;              // 528*128

  hipMemsetAsync(sums, 0, 8 * sizeof(float), stream);

  k_pre<<<1088, 256, 0, stream>>>(x, L, W1a, b1a, W1b, b1b, W2a, b2a, W2b, b2b,
                                  eps1, eps2, Wb1, Wb2, sums);
  k_norm_pool<<<L / 256, 256, 0, stream>>>(x, sums, vb, avg, energy, L);

  k_b1v4<<<L / 256, 256, 0, stream>>>(vb, avg, energy, Wb1, eps1, sums, t1,
                                      psum, psum + 1024, L);
  k_b2nda<<<L / 256, 256, 0, stream>>>(vb, avg, Wb2, eps2, sums, t2,
                                       psum + 2048, psum + 3072, L);

  k_psum<<<4, 1024, 0, stream>>>(psum, sums);
  k_final<<<1024, 256, 0, stream>>>(t1, t2, sums, out, L);
}